// Round 3
// baseline (436.035 us; speedup 1.0000x reference)
//
#include <hip/hip_runtime.h>
#include <hip/hip_bf16.h>
#include <stdint.h>

#define HIDDEN 256
#define NMEM   1024
#define LOG2E  1.44269504088896340736f

typedef __attribute__((ext_vector_type(8)))  short bf16x8;
typedef __attribute__((ext_vector_type(16))) float f32x16;
typedef unsigned short ushort_t;
typedef unsigned int   uint_t;

__device__ __forceinline__ ushort_t f2bf(float f) {
  uint_t u = __builtin_bit_cast(uint_t, f);
  u += 0x7FFFu + ((u >> 16) & 1u);   // RNE (no NaN inputs here)
  return (ushort_t)(u >> 16);
}

__device__ __forceinline__ void gload_lds16(const void* g, void* l) {
  __builtin_amdgcn_global_load_lds(
      (const __attribute__((address_space(1))) uint_t*)g,
      (__attribute__((address_space(3))) uint_t*)l, 16, 0, 0);
}

// ---------------- prep: normalize memories; emit LDS-image layouts -------------
// wsm: 16 tiles x [64 mem][32 chunks of 8 bf16]; chunk c stored at c^(mem&7)
//      (A-operand image for swapped QK: row=mem, k-major)
// wsv: 16 tiles x [256 d][8 chunks of 8 mems]; chunk c stored at c^(d&7)
//      (B-operand image for PV: row=d, mem-major = V^T)
__global__ void prep_kernel(const float* __restrict__ mem,
                            ushort_t* __restrict__ wsm,
                            ushort_t* __restrict__ wsv) {
  const int m = blockIdx.x;
  const int k = threadIdx.x;
  float v = mem[m * HIDDEN + k];
  float ss = v * v;
  #pragma unroll
  for (int off = 1; off < 64; off <<= 1) ss += __shfl_xor(ss, off);
  __shared__ float red[4];
  if ((k & 63) == 0) red[k >> 6] = ss;
  __syncthreads();
  const float tot = red[0] + red[1] + red[2] + red[3];
  const float inv = 1.0f / fmaxf(sqrtf(tot), 1e-12f);
  const ushort_t hn = f2bf(v * inv);
  const ushort_t hv = f2bf(v);
  const int t = m >> 6, mr = m & 63;
  wsm[t * 16384 + mr * 256 + (((k >> 3) ^ (mr & 7)) << 3) + (k & 7)] = hn;
  wsv[t * 16384 + k * 64 + (((mr >> 3) ^ (k & 7)) << 3) + (mr & 7)] = hv;
}

// ---------------- main: fused cosine-softmax memory read -----------------------
// 8 waves x 32 rows = 256 rows/block. 16 KV tiles of 64 mems, dbuf in 128KB LDS.
// Swapped QK (A=m_hat, B=x_hat) -> P lane-local -> permlane32_swap -> PV.
__global__ __launch_bounds__(512, 2) void mem_kernel(
    const float* __restrict__ x, const ushort_t* __restrict__ wsm,
    const ushort_t* __restrict__ wsv, float* __restrict__ out) {
  __shared__ __align__(16) char lds[131072];
  const int tid  = threadIdx.x;
  const int lane = tid & 63;
  const int wave = tid >> 6;
  const int col  = lane & 31;           // QK: x-row | PV: d-col | A-row key
  const int hi   = lane >> 5;
  const int row0 = blockIdx.x * 256 + wave * 32;
  const char* gm = (const char*)wsm;
  const char* gv = (const char*)wsv;

  // ---- stage tile 0 (issue first so it overlaps the x prologue)
  #pragma unroll
  for (int r = 0; r < 4; ++r) {
    const int o = r * 8192 + wave * 1024;
    gload_lds16(gm + o + lane * 16, lds + o);
    gload_lds16(gv + o + lane * 16, lds + 32768 + o);
  }

  // ---- x rows: load, norm, persistent bf16 B-frags (row=col, k=16ks+8hi+j)
  float xf[16][8];
  const float* xr = x + (size_t)(row0 + col) * HIDDEN + hi * 8;
  #pragma unroll
  for (int ks = 0; ks < 16; ++ks) {
    float4 a = *(const float4*)(xr + ks * 16);
    float4 b = *(const float4*)(xr + ks * 16 + 4);
    xf[ks][0]=a.x; xf[ks][1]=a.y; xf[ks][2]=a.z; xf[ks][3]=a.w;
    xf[ks][4]=b.x; xf[ks][5]=b.y; xf[ks][6]=b.z; xf[ks][7]=b.w;
  }
  float ss = 0.f;
  #pragma unroll
  for (int ks = 0; ks < 16; ++ks)
    #pragma unroll
    for (int j = 0; j < 8; ++j) ss += xf[ks][j] * xf[ks][j];
  ss += __shfl_xor(ss, 32);            // lanes l and l+32 hold same-row halves
  const float scale = (2.0f * LOG2E) / fmaxf(sqrtf(ss), 1e-12f);
  bf16x8 xb[16];
  #pragma unroll
  for (int ks = 0; ks < 16; ++ks)
    #pragma unroll
    for (int j = 0; j < 8; ++j) xb[ks][j] = (short)f2bf(xf[ks][j] * scale);

  const f32x16 zz = {0.f,0.f,0.f,0.f, 0.f,0.f,0.f,0.f,
                     0.f,0.f,0.f,0.f, 0.f,0.f,0.f,0.f};
  f32x16 o8[8];
  #pragma unroll
  for (int i = 0; i < 8; ++i) o8[i] = zz;
  float den = 0.f;

  __syncthreads();                      // tile 0 landed (drains vmcnt)

  for (int t = 0; t < 16; ++t) {
    const int mb = (t & 1) << 16;
    const int vbb = mb + 32768;
    if (t < 15) {                       // prefetch next tile into other buffer
      const int nb = ((t & 1) ^ 1) << 16;
      const int go = (t + 1) * 32768;
      #pragma unroll
      for (int r = 0; r < 4; ++r) {
        const int o = r * 8192 + wave * 1024;
        gload_lds16(gm + go + o + lane * 16, lds + nb + o);
        gload_lds16(gv + go + o + lane * 16, lds + nb + 32768 + o);
      }
    }

    #pragma unroll
    for (int half = 0; half < 2; ++half) {
      // ---- QK: S[mem][xrow], A = m_hat (row=half*32+col), B = x_hat (regs)
      const char* ab = lds + mb + (half * 32 + col) * 512;
      const int sk = col & 7;
      f32x16 s0 = zz, s1 = zz;          // 2 acc chains for MFMA ILP
      #pragma unroll
      for (int ks = 0; ks < 8; ++ks) {
        bf16x8 a0 = *(const bf16x8*)(ab + (((4*ks + hi) ^ sk) << 4));
        bf16x8 a1 = *(const bf16x8*)(ab + (((4*ks + 2 + hi) ^ sk) << 4));
        s0 = __builtin_amdgcn_mfma_f32_32x32x16_bf16(a0, xb[2*ks],   s0, 0,0,0);
        s1 = __builtin_amdgcn_mfma_f32_32x32x16_bf16(a1, xb[2*ks+1], s1, 0,0,0);
      }
      // ---- softmax numerator: p = exp2(s); lane holds P[row=col][mem=crow(r,hi)]
      float p[16];
      #pragma unroll
      for (int r = 0; r < 16; ++r) {
        const float pv = exp2f(s0[r] + s1[r]);
        den += pv;
        p[r] = pv;
      }
      // ---- P -> PV A-frags: pack bf16 pairs, permlane32_swap halves (T12)
      bf16x8 pa[2];
      #pragma unroll
      for (int ks = 0; ks < 2; ++ks) {
        const int b0 = ks * 8;
        uint_t w0 = (uint_t)f2bf(p[b0+0]) | ((uint_t)f2bf(p[b0+1]) << 16);
        uint_t w1 = (uint_t)f2bf(p[b0+2]) | ((uint_t)f2bf(p[b0+3]) << 16);
        uint_t w2 = (uint_t)f2bf(p[b0+4]) | ((uint_t)f2bf(p[b0+5]) << 16);
        uint_t w3 = (uint_t)f2bf(p[b0+6]) | ((uint_t)f2bf(p[b0+7]) << 16);
        asm("v_permlane32_swap_b32 %0, %1" : "+v"(w0), "+v"(w2));
        asm("v_permlane32_swap_b32 %0, %1" : "+v"(w1), "+v"(w3));
        uint4 u = {w0, w1, w2, w3};
        pa[ks] = __builtin_bit_cast(bf16x8, u);
      }
      // ---- PV: O += P x V, B = V^T rows (d = d0*32+col)
      #pragma unroll
      for (int ks = 0; ks < 2; ++ks) {
        const int c = half * 4 + ks * 2 + hi;
        #pragma unroll
        for (int d0 = 0; d0 < 8; ++d0) {
          const char* vrow = lds + vbb + (d0 * 32 + col) * 128;
          bf16x8 vf = *(const bf16x8*)(vrow + ((c ^ sk) << 4));
          o8[d0] = __builtin_amdgcn_mfma_f32_32x32x16_bf16(pa[ks], vf, o8[d0], 0,0,0);
        }
      }
    }
    __syncthreads();                    // stage landed + all reads of buffers done
  }

  // ---- denominators: per-lane partial covers hi-half of mems for row `col`
  den += __shfl_xor(den, 32);
  const float rden = 1.0f / den;
  float rdv[16];
  #pragma unroll
  for (int r = 0; r < 16; ++r)
    rdv[r] = __shfl(rden, (r & 3) + 8 * (r >> 2) + 4 * hi);

  // ---- normalize + store: O row = crow(r,hi), d = d0*32+col (32-lane coalesced)
  float* op = out + (size_t)row0 * HIDDEN;
  #pragma unroll
  for (int d0 = 0; d0 < 8; ++d0) {
    #pragma unroll
    for (int r = 0; r < 16; ++r) {
      const int rw = (r & 3) + 8 * (r >> 2) + 4 * hi;
      op[(size_t)rw * HIDDEN + d0 * 32 + col] = o8[d0][r] * rdv[r];
    }
  }
}

extern "C" void kernel_launch(void* const* d_in, const int* in_sizes, int n_in,
                              void* d_out, int out_size, void* d_ws, size_t ws_size,
                              hipStream_t stream) {
  const float* x   = (const float*)d_in[0];
  const float* mem = (const float*)d_in[1];
  float* out = (float*)d_out;
  const int N = in_sizes[0] / HIDDEN;          // 131072

  ushort_t* wsm = (ushort_t*)d_ws;             // 512 KB (m_hat image)
  ushort_t* wsv = wsm + NMEM * HIDDEN;         // 512 KB (V^T image)

  prep_kernel<<<NMEM, HIDDEN, 0, stream>>>(mem, wsm, wsv);
  mem_kernel<<<N / 256, 512, 0, stream>>>(x, wsm, wsv, out);
}